// Round 1
// baseline (253.800 us; speedup 1.0000x reference)
//
#include <hip/hip_runtime.h>
#include <math.h>

// Problem constants
#define TT 8
#define BB 128
#define GG 256
#define DD 64
#define NCH 4     // D chunks
#define CF4 4     // float4s per cell per chunk (16 floats)
#define ST 5      // padded LDS stride in float4s (20 dwords: 8 lanes cover all 32 banks once)

// ws layout: ws[0..6] = global accumulators (zdiff, pres, poolc, obj, fsq, szp, sflow),
//            ws[7]    = completion ticket (as unsigned). Zeroed by hipMemsetAsync each launch.

__device__ inline float wred(float v) {
#pragma unroll
    for (int off = 32; off > 0; off >>= 1) v += __shfl_xor(v, off, 64);
    return v;
}
__device__ inline float dot4(float4 a, float4 b) {
    return a.x * b.x + a.y * b.y + a.z * b.z + a.w * b.w;
}
__device__ inline float4 fabs4(float4 a) {
    return make_float4(fabsf(a.x), fabsf(a.y), fabsf(a.z), fabsf(a.w));
}
__device__ inline float4 max4(float4 a, float4 b) {
    return make_float4(fmaxf(a.x, b.x), fmaxf(a.y, b.y), fmaxf(a.z, b.z), fmaxf(a.w, b.w));
}
__device__ inline float4 scale4(float4 a, float s) {
    return make_float4(a.x * s, a.y * s, a.z * s, a.w * s);
}
__device__ inline float4 sub4(float4 a, float4 b) {
    return make_float4(a.x - b.x, a.y - b.y, a.z - b.z, a.w - b.w);
}

// 3-wide row max via DPP. DPP "rows" are 16 lanes, which exactly match grid rows
// (gj = tid & 15, and tid & 63 preserves the 16-alignment). With old = v and
// bound_ctrl = false, out-of-row lanes receive v (identity for max), so no gj
// masking is needed; SHL/SHR direction convention is irrelevant by symmetry.
__device__ inline float rowmax3(float v) {
    int iv = __float_as_int(v);
    int a = __builtin_amdgcn_update_dpp(iv, iv, 0x101, 0xF, 0xF, false); // row_shl:1
    int c = __builtin_amdgcn_update_dpp(iv, iv, 0x111, 0xF, 0xF, false); // row_shr:1
    return fmaxf(v, fmaxf(__int_as_float(a), __int_as_float(c)));
}
__device__ inline float4 rowmax3_4(float4 v) {
    return make_float4(rowmax3(v.x), rowmax3(v.y), rowmax3(v.z), rowmax3(v.w));
}

// __launch_bounds__(256, 4): 4 waves/EU min -> VGPR capped at 128 -> 4 blocks/CU.
// With LDS at ~23.8 KiB (6 blocks/CU limit), occupancy limit = 4 blocks/CU, so all
// 896 blocks of the grid are co-resident (capacity 1024) -- no second round, no tail.
__global__ __launch_bounds__(256, 4) void pair_kernel(const float* __restrict__ zw,
                                                      const float* __restrict__ zp,
                                                      const float* __restrict__ flow,
                                                      const int* __restrict__ gs,
                                                      float* __restrict__ ws,
                                                      float* __restrict__ out) {
    const int pairIdx = blockIdx.x;            // 0 .. 7*BB-1
    const int t = pairIdx >> 7;                // BB = 128
    const int b = pairIdx & (BB - 1);
    const int tid = threadIdx.x;
    const int gi = tid >> 4, gj = tid & 15;

    __shared__ float4 shB[GG * ST];            // chunk buffer: raw B, then row-max tmp
    __shared__ float pA[GG], pB[GG], nB[GG];
    __shared__ float bred[7][4];

    const float4* gA = (const float4*)zw + (size_t)(t * BB + b) * 1024;
    const float4* gB = gA + (size_t)BB * 1024;

    const float pAc = zp[(size_t)(t * BB + b) * GG + tid];
    const float pBc = zp[(size_t)((t + 1) * BB + b) * GG + tid];
    pA[tid] = pAc;
    pB[tid] = pBc;

    // 9 wrapped neighbors (jnp.roll semantics) + in-bounds bitmask (clamped ops)
    int nbc[9];
    unsigned inbM = 0;
    {
        int m = 0;
#pragma unroll
        for (int di = -1; di <= 1; di++) {
#pragma unroll
            for (int dj = -1; dj <= 1; dj++) {
                nbc[m] = (((gi + di) & 15) << 4) | ((gj + dj) & 15);
                if (((unsigned)(gi + di) < 16u) && ((unsigned)(gj + dj) < 16u))
                    inbM |= (1u << m);
                m++;
            }
        }
    }
    __syncthreads();

    float zdiff = 0.f, sa = 0.f, sb = 0.f, poolDot = 0.f, poolN = 0.f;
    float dots[9] = {0.f, 0.f, 0.f, 0.f, 0.f, 0.f, 0.f, 0.f, 0.f};
    const int sbase = tid * ST;

    // IMPORTANT: unroll 1 -- full unroll hoists all chunks' global loads and
    // spills (round-2 post-mortem: VGPR=256, 293 MB scratch writes).
#pragma unroll 1
    for (int c = 0; c < NCH; c++) {
        float4 aA[CF4], aB[CF4];
#pragma unroll
        for (int q = 0; q < CF4; q++) {
            aA[q] = gA[tid * 16 + c * 4 + q];
            aB[q] = gB[tid * 16 + c * 4 + q];
        }

        // Stage raw B; row-max of wa = pA*|A| computed purely in registers via DPP
        // (replaces the old 20 KiB shW buffer -> halves LDS -> doubles residency).
        float4 rm[CF4];
#pragma unroll
        for (int q = 0; q < CF4; q++) {
            shB[sbase + q] = aB[q];
            rm[q] = rowmax3_4(scale4(fabs4(aA[q]), pAc));
        }
        __syncthreads();

        // register-local stats + center dot
#pragma unroll
        for (int q = 0; q < CF4; q++) {
            float4 d = sub4(aB[q], aA[q]);
            zdiff += dot4(d, d);
            sa += dot4(aA[q], aA[q]);
            sb += dot4(aB[q], aB[q]);
            dots[4] += dot4(aA[q], aB[q]);
        }
        // neighbor dots: A(center, regs) . B(neighbor, LDS)
#pragma unroll
        for (int k = 0; k < 9; k++) {
            if (k == 4) continue;
            int base = nbc[k] * ST;
#pragma unroll
            for (int q = 0; q < CF4; q++) dots[k] += dot4(aA[q], shB[base + q]);
        }
        __syncthreads();   // B-dots done; safe to overwrite shB with row-max tmp

#pragma unroll
        for (int q = 0; q < CF4; q++) shB[sbase + q] = rm[q];
        __syncthreads();

        // clamped col-max, then accumulate pool dot/norm
        float4 sm[CF4];
#pragma unroll
        for (int q = 0; q < CF4; q++) sm[q] = rm[q];
        if (gi > 0) {
            int base = (tid - 16) * ST;
#pragma unroll
            for (int q = 0; q < CF4; q++) sm[q] = max4(sm[q], shB[base + q]);
        }
        if (gi < 15) {
            int base = (tid + 16) * ST;
#pragma unroll
            for (int q = 0; q < CF4; q++) sm[q] = max4(sm[q], shB[base + q]);
        }
#pragma unroll
        for (int q = 0; q < CF4; q++) {
            poolDot += dot4(sm[q], fabs4(aB[q]));
            poolN += dot4(sm[q], sm[q]);
        }
        __syncthreads();   // before next chunk overwrites shB
    }

    // ---- epilogues ----
    nB[tid] = sqrtf(sb);
    __syncthreads();

    // objects
    float prior_n = fmaxf(sqrtf(sa), 1e-8f);
    float sum_sim = 0.f, max_sim = -1e30f;
    bool has = false;
#pragma unroll
    for (int k = 0; k < 9; k++) {
        float nn = fmaxf(nB[nbc[k]], 1e-8f);
        float s = dots[k] / (prior_n * nn);
        if (pB[nbc[k]] > 0.5f) {
            sum_sim += s;
            max_sim = fmaxf(max_sim, s);
            has = true;
        }
    }
    float obj = ((pAc > 0.5f) && has) ? (sum_sim - 5.0f * max_sim) : 0.f;

    // pool
    float na_pool = fmaxf(sqrtf(poolN), 1e-6f);
    float nb_pool = fmaxf(pBc * sqrtf(sb), 1e-6f);
    float poolc = -(pBc * poolDot) / (na_pool * nb_pool) * 0.5f * (pAc + pBc);

    // flow (image t; block t=6 also handles image 7)
    float mx = pAc;
#pragma unroll
    for (int k = 0; k < 9; k++)
        if (k != 4 && ((inbM >> k) & 1u)) mx = fmaxf(mx, pA[nbc[k]]);
    float f = flow[(size_t)(t * BB + b) * GG + tid];
    float fsq = 0.f;
    if (f > 0.5f) { float d = mx - f; fsq = d * d; }
    float szp = pAc, sflow = f;
    if (t == 6) {
        float mxB = pBc;
#pragma unroll
        for (int k = 0; k < 9; k++)
            if (k != 4 && ((inbM >> k) & 1u)) mxB = fmaxf(mxB, pB[nbc[k]]);
        float f7 = flow[(size_t)(7 * BB + b) * GG + tid];
        if (f7 > 0.5f) { float d = mxB - f7; fsq += d * d; }
        szp += pBc;
        sflow += f7;
    }

    // pres triple (t, t+1, t+2) for t <= 5
    float pres = 0.f;
    if (t <= 5) {
        float pC = zp[(size_t)((t + 2) * BB + b) * GG + tid];
        float s02 = pC - pAc;
        float sim = 1.f - s02 * s02;
        float d2 = pC - pBc, d0 = pAc - pBc;
        pres = sim * (d2 * d2 + d0 * d0);
    }

    // ---- block reduce 7 scalars -> device accumulators; last block finalizes ----
    float r[7] = {zdiff, pres, poolc, obj, fsq, szp, sflow};
    int w = tid >> 6, lane = tid & 63;
#pragma unroll
    for (int j = 0; j < 7; j++) {
        float rv = wred(r[j]);
        if (lane == 0) bred[j][w] = rv;
    }
    __syncthreads();
    if (tid < 7) {
        float v = bred[tid][0] + bred[tid][1] + bred[tid][2] + bred[tid][3];
        atomicAdd(&ws[tid], v);   // device-scope float atomic
    }
    __syncthreads();              // drains the wave's atomics (vmcnt 0) before ticket

    if (tid == 0) {
        unsigned old = __hip_atomic_fetch_add((unsigned*)(ws + 7), 1u,
                                              __ATOMIC_ACQ_REL, __HIP_MEMORY_SCOPE_AGENT);
        if (old == (unsigned)(gridDim.x - 1)) {
            // last block: acquire on the ticket RMW orders these loads after all adds
            float s[7];
#pragma unroll
            for (int j = 0; j < 7; j++)
                s[j] = __hip_atomic_load(ws + j, __ATOMIC_RELAXED, __HIP_MEMORY_SCOPE_AGENT);
            float step = (float)gs[0];
            float scale_obj = fminf(1.f, step / 200000.f);
            float scale_flow = fmaxf(0.f, 1.f - step / 100000.f);
            float flow_loss = s[4] + 100.f * fmaxf(0.f, s[5] - s[6]);
            out[0] = s[0]                       // z_what_loss * ADJ_W
                   + s[1]                       // z_pres_loss * PRES_W
                   + s[2]                       // pool (already negated) * POOL_W
                   + s[3] * scale_obj * 10.0f   // objects * OBJ_W
                   + flow_loss * scale_flow;    // FLOW_W = 1
        }
    }
}

extern "C" void kernel_launch(void* const* d_in, const int* in_sizes, int n_in,
                              void* d_out, int out_size, void* d_ws, size_t ws_size,
                              hipStream_t stream) {
    const float* zw = (const float*)d_in[0];
    const float* zp = (const float*)d_in[1];
    const float* fl = (const float*)d_in[2];
    const int* gs = (const int*)d_in[3];
    float* ws = (float*)d_ws;

    // zero the 7 accumulators + ticket each replay (graph-capturable, stream-ordered)
    hipMemsetAsync(d_ws, 0, 8 * sizeof(float), stream);
    pair_kernel<<<(TT - 1) * BB, 256, 0, stream>>>(zw, zp, fl, gs, ws, (float*)d_out);
}

// Round 2
// 142.764 us; speedup vs baseline: 1.7778x; 1.7778x over previous
//
#include <hip/hip_runtime.h>
#include <math.h>

// Problem constants
#define TT 8
#define BB 128
#define GG 256
#define DD 64
#define NCH 4     // D chunks
#define CF4 4     // float4s per cell per chunk (16 floats)
#define ST 5      // padded LDS stride in float4s (20 dwords: 8 lanes cover all 32 banks once)

// ws layout: ws[0..6] = global accumulators (zdiff, pres, poolc, obj, fsq, szp, sflow),
//            ws[7]    = completion ticket (as unsigned). Zeroed by hipMemsetAsync each launch.

__device__ inline float wred(float v) {
#pragma unroll
    for (int off = 32; off > 0; off >>= 1) v += __shfl_xor(v, off, 64);
    return v;
}
__device__ inline float dot4(float4 a, float4 b) {
    return a.x * b.x + a.y * b.y + a.z * b.z + a.w * b.w;
}
__device__ inline float4 fabs4(float4 a) {
    return make_float4(fabsf(a.x), fabsf(a.y), fabsf(a.z), fabsf(a.w));
}
__device__ inline float4 max4(float4 a, float4 b) {
    return make_float4(fmaxf(a.x, b.x), fmaxf(a.y, b.y), fmaxf(a.z, b.z), fmaxf(a.w, b.w));
}
__device__ inline float4 scale4(float4 a, float s) {
    return make_float4(a.x * s, a.y * s, a.z * s, a.w * s);
}
__device__ inline float4 sub4(float4 a, float4 b) {
    return make_float4(a.x - b.x, a.y - b.y, a.z - b.z, a.w - b.w);
}

// 3-wide row max via DPP. DPP "rows" are 16 lanes, which exactly match grid rows
// (gj = tid & 15). With old = v and bound_ctrl = false, out-of-row lanes receive v
// (identity for max), so no gj masking is needed. Verified correct in round 1.
__device__ inline float rowmax3(float v) {
    int iv = __float_as_int(v);
    int a = __builtin_amdgcn_update_dpp(iv, iv, 0x101, 0xF, 0xF, false); // row_shl:1
    int c = __builtin_amdgcn_update_dpp(iv, iv, 0x111, 0xF, 0xF, false); // row_shr:1
    return fmaxf(v, fmaxf(__int_as_float(a), __int_as_float(c)));
}
__device__ inline float4 rowmax3_4(float4 v) {
    return make_float4(rowmax3(v.x), rowmax3(v.y), rowmax3(v.z), rowmax3(v.w));
}

// Plain __launch_bounds__(256): round-1 post-mortem showed the ",4" min-waves arg
// made the backend target 8 waves/EU -> 64 VGPRs -> 326 MB scratch spill (4x slower).
// Plain bound compiles this structure to 128 VGPR, 0 spill (round-0 evidence).
// VGPR=128 -> 4 blocks/CU; LDS=24 KiB -> 6 blocks/CU; limiter 4/CU -> 1024 slots
// >= 896 blocks: entire grid co-resident, no second scheduling round, no tail.
__global__ __launch_bounds__(256) void pair_kernel(const float* __restrict__ zw,
                                                   const float* __restrict__ zp,
                                                   const float* __restrict__ flow,
                                                   const int* __restrict__ gs,
                                                   float* __restrict__ ws,
                                                   float* __restrict__ out) {
    const int pairIdx = blockIdx.x;            // 0 .. 7*BB-1
    const int t = pairIdx >> 7;                // BB = 128
    const int b = pairIdx & (BB - 1);
    const int tid = threadIdx.x;
    const int gi = tid >> 4, gj = tid & 15;

    __shared__ float4 shB[GG * ST];            // chunk buffer: raw B, then row-max tmp
    __shared__ float pA[GG], pB[GG], nB[GG];
    __shared__ float bred[7][4];

    const float4* gA = (const float4*)zw + (size_t)(t * BB + b) * 1024;
    const float4* gB = gA + (size_t)BB * 1024;

    const float pAc = zp[(size_t)(t * BB + b) * GG + tid];
    const float pBc = zp[(size_t)((t + 1) * BB + b) * GG + tid];
    pA[tid] = pAc;
    pB[tid] = pBc;

    // 9 wrapped neighbors (jnp.roll semantics) + in-bounds bitmask (clamped ops)
    int nbc[9];
    unsigned inbM = 0;
    {
        int m = 0;
#pragma unroll
        for (int di = -1; di <= 1; di++) {
#pragma unroll
            for (int dj = -1; dj <= 1; dj++) {
                nbc[m] = (((gi + di) & 15) << 4) | ((gj + dj) & 15);
                if (((unsigned)(gi + di) < 16u) && ((unsigned)(gj + dj) < 16u))
                    inbM |= (1u << m);
                m++;
            }
        }
    }
    __syncthreads();

    float zdiff = 0.f, sa = 0.f, sb = 0.f, poolDot = 0.f, poolN = 0.f;
    float dots[9] = {0.f, 0.f, 0.f, 0.f, 0.f, 0.f, 0.f, 0.f, 0.f};
    const int sbase = tid * ST;

    // IMPORTANT: unroll 1 -- full unroll hoists all chunks' global loads and
    // spills (round-2 post-mortem: VGPR=256, 293 MB scratch writes).
#pragma unroll 1
    for (int c = 0; c < NCH; c++) {
        float4 aA[CF4], aB[CF4];
#pragma unroll
        for (int q = 0; q < CF4; q++) {
            aA[q] = gA[tid * 16 + c * 4 + q];
            aB[q] = gB[tid * 16 + c * 4 + q];
        }

        // Stage raw B; row-max of wa = pA*|A| computed purely in registers via DPP
        // (replaces the old 20 KiB shW buffer -> halves LDS -> doubles residency).
        float4 rm[CF4];
#pragma unroll
        for (int q = 0; q < CF4; q++) {
            shB[sbase + q] = aB[q];
            rm[q] = rowmax3_4(scale4(fabs4(aA[q]), pAc));
        }
        __syncthreads();

        // register-local stats + center dot
#pragma unroll
        for (int q = 0; q < CF4; q++) {
            float4 d = sub4(aB[q], aA[q]);
            zdiff += dot4(d, d);
            sa += dot4(aA[q], aA[q]);
            sb += dot4(aB[q], aB[q]);
            dots[4] += dot4(aA[q], aB[q]);
        }
        // neighbor dots: A(center, regs) . B(neighbor, LDS)
#pragma unroll
        for (int k = 0; k < 9; k++) {
            if (k == 4) continue;
            int base = nbc[k] * ST;
#pragma unroll
            for (int q = 0; q < CF4; q++) dots[k] += dot4(aA[q], shB[base + q]);
        }
        __syncthreads();   // B-dots done; safe to overwrite shB with row-max tmp

#pragma unroll
        for (int q = 0; q < CF4; q++) shB[sbase + q] = rm[q];
        __syncthreads();

        // clamped col-max, then accumulate pool dot/norm
        float4 sm[CF4];
#pragma unroll
        for (int q = 0; q < CF4; q++) sm[q] = rm[q];
        if (gi > 0) {
            int base = (tid - 16) * ST;
#pragma unroll
            for (int q = 0; q < CF4; q++) sm[q] = max4(sm[q], shB[base + q]);
        }
        if (gi < 15) {
            int base = (tid + 16) * ST;
#pragma unroll
            for (int q = 0; q < CF4; q++) sm[q] = max4(sm[q], shB[base + q]);
        }
#pragma unroll
        for (int q = 0; q < CF4; q++) {
            poolDot += dot4(sm[q], fabs4(aB[q]));
            poolN += dot4(sm[q], sm[q]);
        }
        __syncthreads();   // before next chunk overwrites shB
    }

    // ---- epilogues ----
    nB[tid] = sqrtf(sb);
    __syncthreads();

    // objects
    float prior_n = fmaxf(sqrtf(sa), 1e-8f);
    float sum_sim = 0.f, max_sim = -1e30f;
    bool has = false;
#pragma unroll
    for (int k = 0; k < 9; k++) {
        float nn = fmaxf(nB[nbc[k]], 1e-8f);
        float s = dots[k] / (prior_n * nn);
        if (pB[nbc[k]] > 0.5f) {
            sum_sim += s;
            max_sim = fmaxf(max_sim, s);
            has = true;
        }
    }
    float obj = ((pAc > 0.5f) && has) ? (sum_sim - 5.0f * max_sim) : 0.f;

    // pool
    float na_pool = fmaxf(sqrtf(poolN), 1e-6f);
    float nb_pool = fmaxf(pBc * sqrtf(sb), 1e-6f);
    float poolc = -(pBc * poolDot) / (na_pool * nb_pool) * 0.5f * (pAc + pBc);

    // flow (image t; block t=6 also handles image 7)
    float mx = pAc;
#pragma unroll
    for (int k = 0; k < 9; k++)
        if (k != 4 && ((inbM >> k) & 1u)) mx = fmaxf(mx, pA[nbc[k]]);
    float f = flow[(size_t)(t * BB + b) * GG + tid];
    float fsq = 0.f;
    if (f > 0.5f) { float d = mx - f; fsq = d * d; }
    float szp = pAc, sflow = f;
    if (t == 6) {
        float mxB = pBc;
#pragma unroll
        for (int k = 0; k < 9; k++)
            if (k != 4 && ((inbM >> k) & 1u)) mxB = fmaxf(mxB, pB[nbc[k]]);
        float f7 = flow[(size_t)(7 * BB + b) * GG + tid];
        if (f7 > 0.5f) { float d = mxB - f7; fsq += d * d; }
        szp += pBc;
        sflow += f7;
    }

    // pres triple (t, t+1, t+2) for t <= 5
    float pres = 0.f;
    if (t <= 5) {
        float pC = zp[(size_t)((t + 2) * BB + b) * GG + tid];
        float s02 = pC - pAc;
        float sim = 1.f - s02 * s02;
        float d2 = pC - pBc, d0 = pAc - pBc;
        pres = sim * (d2 * d2 + d0 * d0);
    }

    // ---- block reduce 7 scalars -> device accumulators; last block finalizes ----
    float r[7] = {zdiff, pres, poolc, obj, fsq, szp, sflow};
    int w = tid >> 6, lane = tid & 63;
#pragma unroll
    for (int j = 0; j < 7; j++) {
        float rv = wred(r[j]);
        if (lane == 0) bred[j][w] = rv;
    }
    __syncthreads();
    if (tid < 7) {
        float v = bred[tid][0] + bred[tid][1] + bred[tid][2] + bred[tid][3];
        atomicAdd(&ws[tid], v);   // device-scope float atomic
    }
    __syncthreads();              // drains the wave's atomics before ticket

    if (tid == 0) {
        unsigned old = __hip_atomic_fetch_add((unsigned*)(ws + 7), 1u,
                                              __ATOMIC_ACQ_REL, __HIP_MEMORY_SCOPE_AGENT);
        if (old == (unsigned)(gridDim.x - 1)) {
            // last block: acquire on the ticket RMW orders these loads after all adds
            float s[7];
#pragma unroll
            for (int j = 0; j < 7; j++)
                s[j] = __hip_atomic_load(ws + j, __ATOMIC_RELAXED, __HIP_MEMORY_SCOPE_AGENT);
            float step = (float)gs[0];
            float scale_obj = fminf(1.f, step / 200000.f);
            float scale_flow = fmaxf(0.f, 1.f - step / 100000.f);
            float flow_loss = s[4] + 100.f * fmaxf(0.f, s[5] - s[6]);
            out[0] = s[0]                       // z_what_loss * ADJ_W
                   + s[1]                       // z_pres_loss * PRES_W
                   + s[2]                       // pool (already negated) * POOL_W
                   + s[3] * scale_obj * 10.0f   // objects * OBJ_W
                   + flow_loss * scale_flow;    // FLOW_W = 1
        }
    }
}

extern "C" void kernel_launch(void* const* d_in, const int* in_sizes, int n_in,
                              void* d_out, int out_size, void* d_ws, size_t ws_size,
                              hipStream_t stream) {
    const float* zw = (const float*)d_in[0];
    const float* zp = (const float*)d_in[1];
    const float* fl = (const float*)d_in[2];
    const int* gs = (const int*)d_in[3];
    float* ws = (float*)d_ws;

    // zero the 7 accumulators + ticket each replay (graph-capturable, stream-ordered)
    hipMemsetAsync(d_ws, 0, 8 * sizeof(float), stream);
    pair_kernel<<<(TT - 1) * BB, 256, 0, stream>>>(zw, zp, fl, gs, ws, (float*)d_out);
}

// Round 3
// 141.405 us; speedup vs baseline: 1.7948x; 1.0096x over previous
//
#include <hip/hip_runtime.h>
#include <math.h>

// Problem constants
#define TT 8
#define BB 128
#define GG 256
#define DD 64
#define NCH 4     // D chunks
#define CF4 4     // float4s per cell per chunk (16 floats)
#define ST 5      // padded LDS stride in float4s (20 dwords: 8 lanes cover all 32 banks once)

// ws layout: ws[pair*8 + c], c: 0 zdiff, 1 pres, 2 poolc(neg), 3 obj,
//                               4 flow_sq, 5 sum(zp), 6 sum(flow), 7 unused

__device__ inline float wred(float v) {
#pragma unroll
    for (int off = 32; off > 0; off >>= 1) v += __shfl_xor(v, off, 64);
    return v;
}
__device__ inline float dot4(float4 a, float4 b) {
    return a.x * b.x + a.y * b.y + a.z * b.z + a.w * b.w;
}
__device__ inline float4 fabs4(float4 a) {
    return make_float4(fabsf(a.x), fabsf(a.y), fabsf(a.z), fabsf(a.w));
}
__device__ inline float4 max4(float4 a, float4 b) {
    return make_float4(fmaxf(a.x, b.x), fmaxf(a.y, b.y), fmaxf(a.z, b.z), fmaxf(a.w, b.w));
}
__device__ inline float4 scale4(float4 a, float s) {
    return make_float4(a.x * s, a.y * s, a.z * s, a.w * s);
}
__device__ inline float4 sub4(float4 a, float4 b) {
    return make_float4(a.x - b.x, a.y - b.y, a.z - b.z, a.w - b.w);
}

// 3-wide row max via DPP (verified correct in rounds 1-2). DPP "rows" are 16 lanes,
// matching grid rows (gj = tid & 15). old = v, bound_ctrl = false -> out-of-row
// lanes receive v (identity for max), so no gj masking needed.
__device__ inline float rowmax3(float v) {
    int iv = __float_as_int(v);
    int a = __builtin_amdgcn_update_dpp(iv, iv, 0x101, 0xF, 0xF, false); // row_shl:1
    int c = __builtin_amdgcn_update_dpp(iv, iv, 0x111, 0xF, 0xF, false); // row_shr:1
    return fmaxf(v, fmaxf(__int_as_float(a), __int_as_float(c)));
}
__device__ inline float4 rowmax3_4(float4 v) {
    return make_float4(rowmax3(v.x), rowmax3(v.y), rowmax3(v.z), rowmax3(v.w));
}

// Plain __launch_bounds__(256): round-1 showed ",4" min-waves makes the backend
// target 8 waves/EU -> 64 VGPR -> 326 MB spill. Plain bound: ~124-150 VGPR, 0 spill.
// LDS ~44.2 KiB -> 3 blocks/CU (occupancy data from rounds 0/2 says residency is
// latency-limited at ~1.2 blocks/CU anyway, so LDS capacity is free to spend).
// VGPR budget at 3 waves/SIMD is 168/wave -> prefetch registers are occupancy-free.
__global__ __launch_bounds__(256) void pair_kernel(const float* __restrict__ zw,
                                                   const float* __restrict__ zp,
                                                   const float* __restrict__ flow,
                                                   float* __restrict__ ws) {
    const int pairIdx = blockIdx.x;            // 0 .. 7*BB-1
    const int t = pairIdx >> 7;                // BB = 128
    const int b = pairIdx & (BB - 1);
    const int tid = threadIdx.x;
    const int gi = tid >> 4, gj = tid & 15;

    __shared__ float4 shB[GG * ST];            // raw B chunk (neighbor dots)
    __shared__ float4 shM[GG * ST];            // row-max chunk (col-max pass)
    __shared__ float pA[GG], pB[GG], nrmB[GG];
    __shared__ float bred[7][4];

    const float4* gA = (const float4*)zw + (size_t)(t * BB + b) * 1024;
    const float4* gB = gA + (size_t)BB * 1024;

    const float pAc = zp[(size_t)(t * BB + b) * GG + tid];
    const float pBc = zp[(size_t)((t + 1) * BB + b) * GG + tid];
    pA[tid] = pAc;                             // visibility covered by chunk-loop syncs
    pB[tid] = pBc;

    // 9 wrapped neighbors (jnp.roll semantics) + in-bounds bitmask (clamped ops)
    int nbc[9];
    unsigned inbM = 0;
    {
        int m = 0;
#pragma unroll
        for (int di = -1; di <= 1; di++) {
#pragma unroll
            for (int dj = -1; dj <= 1; dj++) {
                nbc[m] = (((gi + di) & 15) << 4) | ((gj + dj) & 15);
                if (((unsigned)(gi + di) < 16u) && ((unsigned)(gj + dj) < 16u))
                    inbM |= (1u << m);
                m++;
            }
        }
    }

    float zdiff = 0.f, sa = 0.f, sb = 0.f, poolDot = 0.f, poolN = 0.f;
    float dots[9] = {0.f, 0.f, 0.f, 0.f, 0.f, 0.f, 0.f, 0.f, 0.f};
    const int sbase = tid * ST;

    // prologue: chunk 0 loads
    float4 aA[CF4], aB[CF4];
#pragma unroll
    for (int q = 0; q < CF4; q++) {
        aA[q] = gA[tid * 16 + q];
        aB[q] = gB[tid * 16 + q];
    }

    // IMPORTANT: unroll 1 -- full unroll hoists all chunks' global loads and spills.
#pragma unroll 1
    for (int c = 0; c < NCH; c++) {
        // software pipeline: issue next chunk's loads first ((c+1)&3 keeps the last
        // iteration's prefetch in-bounds; it redundantly re-reads chunk 0, dead).
        float4 pfA[CF4], pfB[CF4];
        const int cn = (c + 1) & 3;
#pragma unroll
        for (int q = 0; q < CF4; q++) {
            pfA[q] = gA[tid * 16 + cn * 4 + q];
            pfB[q] = gB[tid * 16 + cn * 4 + q];
        }

        // stage raw B and DPP row-max into separate buffers -> one sync serves both
        float4 rm[CF4];
#pragma unroll
        for (int q = 0; q < CF4; q++) {
            shB[sbase + q] = aB[q];
            rm[q] = rowmax3_4(scale4(fabs4(aA[q]), pAc));
            shM[sbase + q] = rm[q];
        }
        __syncthreads();

        // register-local stats + center dot
#pragma unroll
        for (int q = 0; q < CF4; q++) {
            float4 d = sub4(aB[q], aA[q]);
            zdiff += dot4(d, d);
            sa += dot4(aA[q], aA[q]);
            sb += dot4(aB[q], aB[q]);
            dots[4] += dot4(aA[q], aB[q]);
        }
        // neighbor dots: A(center, regs) . B(neighbor, shB)
#pragma unroll
        for (int k = 0; k < 9; k++) {
            if (k == 4) continue;
            int base = nbc[k] * ST;
#pragma unroll
            for (int q = 0; q < CF4; q++) dots[k] += dot4(aA[q], shB[base + q]);
        }
        // clamped col-max of row-max (in place on rm), then pool accumulation
        if (gi > 0) {
            int base = (tid - 16) * ST;
#pragma unroll
            for (int q = 0; q < CF4; q++) rm[q] = max4(rm[q], shM[base + q]);
        }
        if (gi < 15) {
            int base = (tid + 16) * ST;
#pragma unroll
            for (int q = 0; q < CF4; q++) rm[q] = max4(rm[q], shM[base + q]);
        }
#pragma unroll
        for (int q = 0; q < CF4; q++) {
            poolDot += dot4(rm[q], fabs4(aB[q]));
            poolN += dot4(rm[q], rm[q]);
        }
        __syncthreads();   // all reads of shB/shM done before next chunk's stores

        // rotate pipeline registers
#pragma unroll
        for (int q = 0; q < CF4; q++) { aA[q] = pfA[q]; aB[q] = pfB[q]; }
    }

    // ---- epilogues ----
    nrmB[tid] = sqrtf(sb);
    __syncthreads();

    // objects
    float prior_n = fmaxf(sqrtf(sa), 1e-8f);
    float sum_sim = 0.f, max_sim = -1e30f;
    bool has = false;
#pragma unroll
    for (int k = 0; k < 9; k++) {
        float nn = fmaxf(nrmB[nbc[k]], 1e-8f);
        float s = dots[k] / (prior_n * nn);
        if (pB[nbc[k]] > 0.5f) {
            sum_sim += s;
            max_sim = fmaxf(max_sim, s);
            has = true;
        }
    }
    float obj = ((pAc > 0.5f) && has) ? (sum_sim - 5.0f * max_sim) : 0.f;

    // pool
    float na_pool = fmaxf(sqrtf(poolN), 1e-6f);
    float nb_pool = fmaxf(pBc * sqrtf(sb), 1e-6f);
    float poolc = -(pBc * poolDot) / (na_pool * nb_pool) * 0.5f * (pAc + pBc);

    // flow (image t; block t=6 also handles image 7)
    float mx = pAc;
#pragma unroll
    for (int k = 0; k < 9; k++)
        if (k != 4 && ((inbM >> k) & 1u)) mx = fmaxf(mx, pA[nbc[k]]);
    float f = flow[(size_t)(t * BB + b) * GG + tid];
    float fsq = 0.f;
    if (f > 0.5f) { float d = mx - f; fsq = d * d; }
    float szp = pAc, sflow = f;
    if (t == 6) {
        float mxB = pBc;
#pragma unroll
        for (int k = 0; k < 9; k++)
            if (k != 4 && ((inbM >> k) & 1u)) mxB = fmaxf(mxB, pB[nbc[k]]);
        float f7 = flow[(size_t)(7 * BB + b) * GG + tid];
        if (f7 > 0.5f) { float d = mxB - f7; fsq += d * d; }
        szp += pBc;
        sflow += f7;
    }

    // pres triple (t, t+1, t+2) for t <= 5
    float pres = 0.f;
    if (t <= 5) {
        float pC = zp[(size_t)((t + 2) * BB + b) * GG + tid];
        float s02 = pC - pAc;
        float sim = 1.f - s02 * s02;
        float d2 = pC - pBc, d0 = pAc - pBc;
        pres = sim * (d2 * d2 + d0 * d0);
    }

    // ---- block reduce 7 scalars -> private ws slot (no atomics) ----
    float r[7] = {zdiff, pres, poolc, obj, fsq, szp, sflow};
    int w = tid >> 6, lane = tid & 63;
#pragma unroll
    for (int j = 0; j < 7; j++) {
        float rv = wred(r[j]);
        if (lane == 0) bred[j][w] = rv;
    }
    __syncthreads();
    if (tid < 7)
        ws[pairIdx * 8 + tid] = bred[tid][0] + bred[tid][1] + bred[tid][2] + bred[tid][3];
}

__global__ __launch_bounds__(256) void final_kernel(const float* __restrict__ ws,
                                                    const int* __restrict__ gs,
                                                    float* __restrict__ out) {
    const int tid = threadIdx.x;
    __shared__ float bred[7][4];
    float c[7] = {0.f, 0.f, 0.f, 0.f, 0.f, 0.f, 0.f};
    for (int p = tid; p < (TT - 1) * BB; p += 256) {
        const float* r = ws + p * 8;
#pragma unroll
        for (int j = 0; j < 7; j++) c[j] += r[j];
    }
    int w = tid >> 6, lane = tid & 63;
#pragma unroll
    for (int j = 0; j < 7; j++) {
        float rv = wred(c[j]);
        if (lane == 0) bred[j][w] = rv;
    }
    __syncthreads();
    if (tid == 0) {
        float s[7];
#pragma unroll
        for (int j = 0; j < 7; j++) s[j] = bred[j][0] + bred[j][1] + bred[j][2] + bred[j][3];
        float step = (float)gs[0];
        float scale_obj = fminf(1.f, step / 200000.f);
        float scale_flow = fmaxf(0.f, 1.f - step / 100000.f);
        float flow_loss = s[4] + 100.f * fmaxf(0.f, s[5] - s[6]);
        out[0] = s[0]                       // z_what_loss * ADJ_W
               + s[1]                       // z_pres_loss * PRES_W
               + s[2]                       // pool (already negated) * POOL_W
               + s[3] * scale_obj * 10.0f   // objects * OBJ_W
               + flow_loss * scale_flow;    // FLOW_W = 1
    }
}

extern "C" void kernel_launch(void* const* d_in, const int* in_sizes, int n_in,
                              void* d_out, int out_size, void* d_ws, size_t ws_size,
                              hipStream_t stream) {
    const float* zw = (const float*)d_in[0];
    const float* zp = (const float*)d_in[1];
    const float* fl = (const float*)d_in[2];
    const int* gs = (const int*)d_in[3];
    float* ws = (float*)d_ws;

    pair_kernel<<<(TT - 1) * BB, 256, 0, stream>>>(zw, zp, fl, ws);
    final_kernel<<<1, 256, 0, stream>>>(ws, gs, (float*)d_out);
}

// Round 4
// 127.840 us; speedup vs baseline: 1.9853x; 1.1061x over previous
//
#include <hip/hip_runtime.h>
#include <math.h>

// Problem constants
#define TT 8
#define BB 128
#define GG 256
#define DD 64
#define NCH 4     // D chunks
#define CF4 4     // float4s per cell per chunk (16 floats)
#define ST 5      // padded LDS stride in float4s (20 dwords: 8 lanes cover all 32 banks once)

// ws layout: ws[pair*8 + c], c: 0 zdiff, 1 pres, 2 poolc(neg), 3 obj,
//                               4 flow_sq, 5 sum(zp), 6 sum(flow), 7 unused
// Round-2 lesson: contended device atomics in the block epilogue cost ~15 us;
// private ws slots + 1-block final_kernel is strictly better.

__device__ inline float wred(float v) {
#pragma unroll
    for (int off = 32; off > 0; off >>= 1) v += __shfl_xor(v, off, 64);
    return v;
}
__device__ inline float dot4(float4 a, float4 b) {
    return a.x * b.x + a.y * b.y + a.z * b.z + a.w * b.w;
}
__device__ inline float4 fabs4(float4 a) {
    return make_float4(fabsf(a.x), fabsf(a.y), fabsf(a.z), fabsf(a.w));
}
__device__ inline float4 max4(float4 a, float4 b) {
    return make_float4(fmaxf(a.x, b.x), fmaxf(a.y, b.y), fmaxf(a.z, b.z), fmaxf(a.w, b.w));
}
__device__ inline float4 scale4(float4 a, float s) {
    return make_float4(a.x * s, a.y * s, a.z * s, a.w * s);
}
__device__ inline float4 sub4(float4 a, float4 b) {
    return make_float4(a.x - b.x, a.y - b.y, a.z - b.z, a.w - b.w);
}

// 3-wide row max via DPP (verified rounds 1-3). DPP "rows" are 16 lanes, matching
// grid rows (gj = tid & 15). old = v, bound_ctrl = false -> out-of-row lanes get v
// (identity for max): clamped semantics for free.
__device__ inline float rowmax3(float v) {
    int iv = __float_as_int(v);
    int a = __builtin_amdgcn_update_dpp(iv, iv, 0x101, 0xF, 0xF, false); // row_shl:1
    int c = __builtin_amdgcn_update_dpp(iv, iv, 0x111, 0xF, 0xF, false); // row_shr:1
    return fmaxf(v, fmaxf(__int_as_float(a), __int_as_float(c)));
}
__device__ inline float4 rowmax3_4(float4 v) {
    return make_float4(rowmax3(v.x), rowmax3(v.y), rowmax3(v.z), rowmax3(v.w));
}

// VGPR budget note (round-1/round-3 post-mortems):
//  - NEVER pass a min-waves arg: ",4" drove the target to 64 VGPR -> 326 MB spill.
//  - NO register prefetch/rotation: pfA/pfB pushed VGPR 124 -> 136, crossing the
//    128 cliff (4 -> 3 waves/SIMD) and regressed 11%. This structure measures ~124.
__global__ __launch_bounds__(256) void pair_kernel(const float* __restrict__ zw,
                                                   const float* __restrict__ zp,
                                                   const float* __restrict__ flow,
                                                   float* __restrict__ ws) {
    const int pairIdx = blockIdx.x;            // 0 .. 7*BB-1
    const int t = pairIdx >> 7;                // BB = 128
    const int b = pairIdx & (BB - 1);
    const int tid = threadIdx.x;
    const int gi = tid >> 4, gj = tid & 15;

    __shared__ float4 shB[GG * ST];            // raw B chunk (neighbor dots)
    __shared__ float4 shM[GG * ST];            // row-max chunk (col-max pass)
    __shared__ float pA[GG], pB[GG], nrmB[GG];
    __shared__ float bred[7][4];

    const float4* gA = (const float4*)zw + (size_t)(t * BB + b) * 1024;
    const float4* gB = gA + (size_t)BB * 1024;

    const float pAc = zp[(size_t)(t * BB + b) * GG + tid];
    const float pBc = zp[(size_t)((t + 1) * BB + b) * GG + tid];
    pA[tid] = pAc;                             // visibility covered by chunk-loop syncs
    pB[tid] = pBc;

    // 9 wrapped neighbors (jnp.roll semantics) + in-bounds bitmask (clamped ops)
    int nbc[9];
    unsigned inbM = 0;
    {
        int m = 0;
#pragma unroll
        for (int di = -1; di <= 1; di++) {
#pragma unroll
            for (int dj = -1; dj <= 1; dj++) {
                nbc[m] = (((gi + di) & 15) << 4) | ((gj + dj) & 15);
                if (((unsigned)(gi + di) < 16u) && ((unsigned)(gj + dj) < 16u))
                    inbM |= (1u << m);
                m++;
            }
        }
    }

    float zdiff = 0.f, sa = 0.f, sb = 0.f, poolDot = 0.f, poolN = 0.f;
    float dots[9] = {0.f, 0.f, 0.f, 0.f, 0.f, 0.f, 0.f, 0.f, 0.f};
    const int sbase = tid * ST;

    // IMPORTANT: unroll 1 -- full unroll hoists all chunks' global loads and spills.
#pragma unroll 1
    for (int c = 0; c < NCH; c++) {
        float4 aA[CF4], aB[CF4];
#pragma unroll
        for (int q = 0; q < CF4; q++) {
            aA[q] = gA[tid * 16 + c * 4 + q];
            aB[q] = gB[tid * 16 + c * 4 + q];
        }

        // stage raw B and DPP row-max into separate buffers -> one sync serves both
        float4 rm[CF4];
#pragma unroll
        for (int q = 0; q < CF4; q++) {
            shB[sbase + q] = aB[q];
            rm[q] = rowmax3_4(scale4(fabs4(aA[q]), pAc));
            shM[sbase + q] = rm[q];
        }
        // register-local stats + center dot (no LDS dependence; also gives waves
        // arriving early at the barrier useful work in-flight)
#pragma unroll
        for (int q = 0; q < CF4; q++) {
            float4 d = sub4(aB[q], aA[q]);
            zdiff += dot4(d, d);
            sa += dot4(aA[q], aA[q]);
            sb += dot4(aB[q], aB[q]);
            dots[4] += dot4(aA[q], aB[q]);
        }
        __syncthreads();

        // neighbor dots: A(center, regs) . B(neighbor, shB)
#pragma unroll
        for (int k = 0; k < 9; k++) {
            if (k == 4) continue;
            int base = nbc[k] * ST;
#pragma unroll
            for (int q = 0; q < CF4; q++) dots[k] += dot4(aA[q], shB[base + q]);
        }
        // clamped col-max of row-max (in place on rm), then pool accumulation
        if (gi > 0) {
            int base = (tid - 16) * ST;
#pragma unroll
            for (int q = 0; q < CF4; q++) rm[q] = max4(rm[q], shM[base + q]);
        }
        if (gi < 15) {
            int base = (tid + 16) * ST;
#pragma unroll
            for (int q = 0; q < CF4; q++) rm[q] = max4(rm[q], shM[base + q]);
        }
#pragma unroll
        for (int q = 0; q < CF4; q++) {
            poolDot += dot4(rm[q], fabs4(aB[q]));
            poolN += dot4(rm[q], rm[q]);
        }
        __syncthreads();   // all reads of shB/shM done before next chunk's stores
    }

    // ---- epilogues ----
    nrmB[tid] = sqrtf(sb);
    __syncthreads();

    // objects
    float prior_n = fmaxf(sqrtf(sa), 1e-8f);
    float sum_sim = 0.f, max_sim = -1e30f;
    bool has = false;
#pragma unroll
    for (int k = 0; k < 9; k++) {
        float nn = fmaxf(nrmB[nbc[k]], 1e-8f);
        float s = dots[k] / (prior_n * nn);
        if (pB[nbc[k]] > 0.5f) {
            sum_sim += s;
            max_sim = fmaxf(max_sim, s);
            has = true;
        }
    }
    float obj = ((pAc > 0.5f) && has) ? (sum_sim - 5.0f * max_sim) : 0.f;

    // pool
    float na_pool = fmaxf(sqrtf(poolN), 1e-6f);
    float nb_pool = fmaxf(pBc * sqrtf(sb), 1e-6f);
    float poolc = -(pBc * poolDot) / (na_pool * nb_pool) * 0.5f * (pAc + pBc);

    // flow (image t; block t=6 also handles image 7)
    float mx = pAc;
#pragma unroll
    for (int k = 0; k < 9; k++)
        if (k != 4 && ((inbM >> k) & 1u)) mx = fmaxf(mx, pA[nbc[k]]);
    float f = flow[(size_t)(t * BB + b) * GG + tid];
    float fsq = 0.f;
    if (f > 0.5f) { float d = mx - f; fsq = d * d; }
    float szp = pAc, sflow = f;
    if (t == 6) {
        float mxB = pBc;
#pragma unroll
        for (int k = 0; k < 9; k++)
            if (k != 4 && ((inbM >> k) & 1u)) mxB = fmaxf(mxB, pB[nbc[k]]);
        float f7 = flow[(size_t)(7 * BB + b) * GG + tid];
        if (f7 > 0.5f) { float d = mxB - f7; fsq += d * d; }
        szp += pBc;
        sflow += f7;
    }

    // pres triple (t, t+1, t+2) for t <= 5
    float pres = 0.f;
    if (t <= 5) {
        float pC = zp[(size_t)((t + 2) * BB + b) * GG + tid];
        float s02 = pC - pAc;
        float sim = 1.f - s02 * s02;
        float d2 = pC - pBc, d0 = pAc - pBc;
        pres = sim * (d2 * d2 + d0 * d0);
    }

    // ---- block reduce 7 scalars -> private ws slot (no atomics) ----
    float r[7] = {zdiff, pres, poolc, obj, fsq, szp, sflow};
    int w = tid >> 6, lane = tid & 63;
#pragma unroll
    for (int j = 0; j < 7; j++) {
        float rv = wred(r[j]);
        if (lane == 0) bred[j][w] = rv;
    }
    __syncthreads();
    if (tid < 7)
        ws[pairIdx * 8 + tid] = bred[tid][0] + bred[tid][1] + bred[tid][2] + bred[tid][3];
}

__global__ __launch_bounds__(256) void final_kernel(const float* __restrict__ ws,
                                                    const int* __restrict__ gs,
                                                    float* __restrict__ out) {
    const int tid = threadIdx.x;
    __shared__ float bred[7][4];
    float c[7] = {0.f, 0.f, 0.f, 0.f, 0.f, 0.f, 0.f};
    for (int p = tid; p < (TT - 1) * BB; p += 256) {
        const float* r = ws + p * 8;
#pragma unroll
        for (int j = 0; j < 7; j++) c[j] += r[j];
    }
    int w = tid >> 6, lane = tid & 63;
#pragma unroll
    for (int j = 0; j < 7; j++) {
        float rv = wred(c[j]);
        if (lane == 0) bred[j][w] = rv;
    }
    __syncthreads();
    if (tid == 0) {
        float s[7];
#pragma unroll
        for (int j = 0; j < 7; j++) s[j] = bred[j][0] + bred[j][1] + bred[j][2] + bred[j][3];
        float step = (float)gs[0];
        float scale_obj = fminf(1.f, step / 200000.f);
        float scale_flow = fmaxf(0.f, 1.f - step / 100000.f);
        float flow_loss = s[4] + 100.f * fmaxf(0.f, s[5] - s[6]);
        out[0] = s[0]                       // z_what_loss * ADJ_W
               + s[1]                       // z_pres_loss * PRES_W
               + s[2]                       // pool (already negated) * POOL_W
               + s[3] * scale_obj * 10.0f   // objects * OBJ_W
               + flow_loss * scale_flow;    // FLOW_W = 1
    }
}

extern "C" void kernel_launch(void* const* d_in, const int* in_sizes, int n_in,
                              void* d_out, int out_size, void* d_ws, size_t ws_size,
                              hipStream_t stream) {
    const float* zw = (const float*)d_in[0];
    const float* zp = (const float*)d_in[1];
    const float* fl = (const float*)d_in[2];
    const int* gs = (const int*)d_in[3];
    float* ws = (float*)d_ws;

    pair_kernel<<<(TT - 1) * BB, 256, 0, stream>>>(zw, zp, fl, ws);
    final_kernel<<<1, 256, 0, stream>>>(ws, gs, (float*)d_out);
}